// Round 3
// baseline (11.948 us; speedup 1.0000x reference)
//
#include <hip/hip_runtime.h>

#define LL 8192
#define PP 8188   // L - K + 1

// Closed form of the 5-qubit windowed circuit:
//   c_i = rsqrt(1+x_i^2)                  = cos(atan x_i)
//   g_i = rsqrt((1+x_i^2)(1+x_i^4))       = c_i * cos(atan x_i^2)
//   e_i = x_i * g_i
//   C   = c_{p+2} * c_{p+3} * c_{p+4}
//   z_p = cos(th)*c_{p+1}*C - sin(th)*e_p*e_{p+1}*(cos(phi) - sin(phi)*x_{p+1}^2*C)
// (omega cancels exactly.)
__global__ __launch_bounds__(256) void qconv_kernel(
    const float* __restrict__ x, const float* __restrict__ w, float* __restrict__ out)
{
    int t = blockIdx.x * 256 + threadIdx.x;   // 65536 threads
    int b = t >> 10;                          // row (64)
    int chunk = t & 1023;                     // 1024 chunks/row
    int p0 = chunk << 3;                      // 8 outputs per thread

    float phi = w[0], theta = w[1];
    float st, ct, sp, cp;
    sincosf(theta, &st, &ct);
    sincosf(phi, &sp, &cp);

    const bool tail = (p0 + 8 > PP);          // last chunk: 4 outputs, 8 loads
    const float* xp = x + b * LL + p0;
    float4 u0 = *(const float4*)(xp);
    float4 u1 = *(const float4*)(xp + 4);
    float4 u2 = tail ? u1 : *(const float4*)(xp + 8);
    float xv[12] = {u0.x, u0.y, u0.z, u0.w, u1.x, u1.y, u1.z, u1.w,
                    u2.x, u2.y, u2.z, u2.w};

    float c[12], e[12], f[12];
#pragma unroll
    for (int i = 0; i < 12; ++i) {
        float xx = xv[i];
        float x2 = xx * xx;
        float a1 = 1.0f + x2;
        float ci = rsqrtf(a1);
        float gi = rsqrtf(a1 * (1.0f + x2 * x2));
        c[i] = ci;
        e[i] = xx * gi;
        f[i] = x2;
    }

    float z[8];
#pragma unroll
    for (int k = 0; k < 8; ++k) {
        float C = c[k + 2] * c[k + 3] * c[k + 4];
        z[k] = ct * c[k + 1] * C
             - st * e[k] * e[k + 1] * (cp - sp * f[k + 1] * C);
    }

    float* op = out + b * PP + p0;
    *(float4*)(op) = make_float4(z[0], z[1], z[2], z[3]);
    if (!tail)
        *(float4*)(op + 4) = make_float4(z[4], z[5], z[6], z[7]);
}

extern "C" void kernel_launch(void* const* d_in, const int* in_sizes, int n_in,
                              void* d_out, int out_size, void* d_ws, size_t ws_size,
                              hipStream_t stream) {
    const float* x = (const float*)d_in[0];
    const float* w = (const float*)d_in[1];
    float* out = (float*)d_out;
    qconv_kernel<<<dim3(256), dim3(256), 0, stream>>>(x, w, out);
}

// Round 4
// 9.486 us; speedup vs baseline: 1.2596x; 1.2596x over previous
//
#include <hip/hip_runtime.h>

#define LL 8192
#define PP 8188   // L - K + 1

// Closed form of the 5-qubit windowed circuit:
//   c_i = rsqrt(1+x_i^2)                  = cos(atan x_i)
//   e_i = x_i * rsqrt((1+x_i^2)(1+x_i^4)) = sin(atan x_i)*cos(atan x_i^2)
//   C   = c_{p+2} * c_{p+3} * c_{p+4}
//   z_p = cos(th)*c_{p+1}*C - sin(th)*e_p*e_{p+1}*(cos(phi) - sin(phi)*x_{p+1}^2*C)
// (omega cancels exactly.)
__global__ __launch_bounds__(256) void qconv_kernel(
    const float* __restrict__ x, const float* __restrict__ w, float* __restrict__ out)
{
    int t = blockIdx.x * 256 + threadIdx.x;   // 131072 threads
    int b = t >> 11;                          // row (64)
    int chunk = t & 2047;                     // 2048 chunks/row
    int p0 = chunk << 2;                      // 4 outputs per thread
    if (p0 >= PP) return;                     // chunk 2047 fully invalid

    float phi = w[0], theta = w[1];
    float st, ct, sp, cp;
    sincosf(theta, &st, &ct);
    sincosf(phi, &sp, &cp);

    const float* xp = x + b * LL + p0;
    float4 u0 = *(const float4*)(xp);
    float4 u1 = *(const float4*)(xp + 4);
    float xv[8] = {u0.x, u0.y, u0.z, u0.w, u1.x, u1.y, u1.z, u1.w};

    float c[8], e[8], f[8];
#pragma unroll
    for (int i = 0; i < 8; ++i) {
        float xx = xv[i];
        float x2 = xx * xx;
        float a1 = 1.0f + x2;
        c[i] = rsqrtf(a1);
        e[i] = xx * rsqrtf(a1 * (1.0f + x2 * x2));
        f[i] = x2;
    }

    float4 z;
    float* zp = &z.x;
#pragma unroll
    for (int k = 0; k < 4; ++k) {
        float C = c[k + 2] * c[k + 3] * c[k + 4];
        zp[k] = ct * c[k + 1] * C
              - st * e[k] * e[k + 1] * (cp - sp * f[k + 1] * C);
    }

    *(float4*)(out + b * PP + p0) = z;
}

extern "C" void kernel_launch(void* const* d_in, const int* in_sizes, int n_in,
                              void* d_out, int out_size, void* d_ws, size_t ws_size,
                              hipStream_t stream) {
    const float* x = (const float*)d_in[0];
    const float* w = (const float*)d_in[1];
    float* out = (float*)d_out;
    qconv_kernel<<<dim3(512), dim3(256), 0, stream>>>(x, w, out);
}